// Round 24
// baseline (974.312 us; speedup 1.0000x reference)
//
#include <hip/hip_runtime.h>

#define HID 256
#define BATCH 512
#define MENC 16
#define HWIN 25
#define SALSZ 4096
#define BH (BATCH * HID)   // 131072

typedef __attribute__((ext_vector_type(8))) short bf16x8;
typedef __attribute__((ext_vector_type(4))) float f32x4;

__device__ __forceinline__ float sigmf(float x) { return 1.0f / (1.0f + __expf(-x)); }
__device__ __forceinline__ ushort f2bf(float f) {
    uint32_t u = __float_as_uint(f);
    return (ushort)((u + 0x7fffu + ((u >> 16) & 1u)) >> 16);   // RNE
}

#define GLOAD_LDS(gp, lp) \
    __builtin_amdgcn_global_load_lds((const __attribute__((address_space(1))) void*)(gp), \
                                     (__attribute__((address_space(3))) void*)(lp), 16, 0, 0)

// ---- write-through stores for cross-block exchange (L3-visible; R7/R10-proven) ----
__device__ __forceinline__ void st_u64(void* p, unsigned long long v) {
    __hip_atomic_store((unsigned long long*)p, v, __ATOMIC_RELAXED, __HIP_MEMORY_SCOPE_AGENT);
}
__device__ __forceinline__ void st_f32(float* p, float v) {
    __hip_atomic_store(p, v, __ATOMIC_RELAXED, __HIP_MEMORY_SCOPE_AGENT);
}

// ---- split fence-free barrier (R14-proven) ----
__device__ __forceinline__ void gbar_arrive(unsigned int* slot)
{
    __syncthreads();    // drains vmcnt: this block's stores are L3-acked
    if (threadIdx.x == 0) atomicAdd(slot, 1u);
}
__device__ __forceinline__ void gbar_wait(unsigned int* slot, unsigned int nblk)
{
    if (threadIdx.x == 0) {
        while (__hip_atomic_load(slot, __ATOMIC_RELAXED, __HIP_MEMORY_SCOPE_AGENT) < nblk)
            __builtin_amdgcn_s_sleep(1);
    }
    __syncthreads();
}

// ---- W tile staging for chains: [64][256] bf16, XOR-swizzled 16B units ----
__device__ __forceinline__ void stage_wtile(const ushort* Wsrc, int ldw, int u0,
                                            ushort* lds, int lane, int wq)
{
    const int sub = lane >> 5, uu = lane & 31;
#pragma unroll
    for (int i = 0; i < 8; ++i) {
        const int row = i * 8 + wq * 2 + sub;
        const int su  = uu ^ (row & 7);
        const int gr  = (row >> 4) * HID + u0 + (row & 15);
        GLOAD_LDS(Wsrc + (size_t)gr * ldw + su * 8, lds + i * 2048 + wq * 512);
    }
}

// ---- chain cell quarter: H from global, W from swizzled LDS; 32 MFMA/wave ----
__device__ __forceinline__ void cell_g(const ushort* hrow0, int ldh,
                                       const ushort* WsL, f32x4 acc[4], int lane)
{
    const int fr = lane & 15, fq = lane >> 4;
    const ushort* hrow = hrow0 + (size_t)fr * ldh;
#pragma unroll
    for (int ks = 0; ks < 8; ++ks) {
        const bf16x8 af = *(const bf16x8*)(hrow + ks * 32 + fq * 8);
#pragma unroll
        for (int g = 0; g < 4; ++g) {
            const int vr = g * 16 + fr;
            const bf16x8 bf = *(const bf16x8*)(WsL + vr * 256 + (((ks * 4 + fq)) ^ (vr & 7)) * 8);
            acc[g] = __builtin_amdgcn_mfma_f32_16x16x32_bf16(af, bf, acc[g], 0, 0, 0);
        }
    }
}

// ---------------- fp32 -> bf16, 9 weight segments in one launch ----------------
struct Cvt9 {
    const float* s[9];
    ushort*      d[9];
    int          end[9];
};
__global__ __launch_bounds__(256)
void cvt_multi(Cvt9 A)
{
    int i = blockIdx.x * 256 + threadIdx.x;
    if (i >= A.end[8]) return;
    int seg = 0, beg = 0;
#pragma unroll
    for (int k = 0; k < 8; ++k)
        if (i >= A.end[k]) { seg = k + 1; beg = A.end[k]; }
    const int j = i - beg;
    const float4 v = *(const float4*)(A.s[seg] + (size_t)j * 4);
    *(ushort4*)(A.d[seg] + (size_t)j * 4) = make_ushort4(f2bf(v.x), f2bf(v.y), f2bf(v.z), f2bf(v.w));
}

// ======== 128x128 GEMM body, BK=64; fused fp32->bf16 A (R20-verified) ========
__device__ __forceinline__ void loadA128(const float* Ag, int lda, int tid, float4 ra[4])
{
#pragma unroll
    for (int j = 0; j < 2; ++j) {
        const int idx = j * 512 + tid;
        const int row = idx >> 3, u = idx & 7;
        const int su = (u ^ (row & 7)) * 8;
        ra[2 * j + 0] = *(const float4*)(Ag + (size_t)row * lda + su);
        ra[2 * j + 1] = *(const float4*)(Ag + (size_t)row * lda + su + 4);
    }
}
__device__ __forceinline__ void writeA128(const float4 ra[4], ushort* Al, int tid)
{
#pragma unroll
    for (int j = 0; j < 2; ++j) {
        const int idx = j * 512 + tid;
        uint4 v;
        v.x = (uint)f2bf(ra[2 * j].x) | ((uint)f2bf(ra[2 * j].y) << 16);
        v.y = (uint)f2bf(ra[2 * j].z) | ((uint)f2bf(ra[2 * j].w) << 16);
        v.z = (uint)f2bf(ra[2 * j + 1].x) | ((uint)f2bf(ra[2 * j + 1].y) << 16);
        v.w = (uint)f2bf(ra[2 * j + 1].z) | ((uint)f2bf(ra[2 * j + 1].w) << 16);
        *(uint4*)(Al + idx * 8) = v;
    }
}
__device__ __forceinline__ void stageB128(const ushort* Bg, int ldw, ushort* Bl, int tid)
{
#pragma unroll
    for (int j = 0; j < 2; ++j) {
        const int idx = j * 512 + tid;
        const int row = idx >> 3, u = idx & 7;
        const int su = (u ^ (row & 7)) * 8;
        GLOAD_LDS(Bg + (size_t)row * ldw + su, Bl + idx * 8);
    }
}

__device__ __forceinline__ void gemm128f_body(
    const float* __restrict__ A, const ushort* __restrict__ W, float* __restrict__ C,
    int lda, int ldw, int ldc, int K, int gx, int nwg, int bid,
    ushort* AsB, ushort* BsB, int tid)
{
    const int lane = tid & 63, wid = tid >> 6;
    {   // bijective XCD-chunked swizzle within this job's sub-grid
        const int q = nwg >> 3, r = nwg & 7;
        const int xcd = bid & 7, o = bid >> 3;
        bid = (xcd < r) ? xcd * (q + 1) + o : r * (q + 1) + (xcd - r) * q + o;
    }
    const int m0 = (bid / gx) * 128, n0 = (bid % gx) * 128;

    const int wr = wid >> 1, wc = wid & 1;     // 4m x 2n wave grid
    const int fr = lane & 15, fq = lane >> 4;

    f32x4 acc[2][4] = {};
    const int nt = K / 64;
    const float*  Ab0 = A + (size_t)m0 * lda;
    const ushort* Bb0 = W + (size_t)n0 * ldw;

    float4 ra[4];
    loadA128(Ab0, lda, tid, ra);
    stageB128(Bb0, ldw, BsB, tid);
    writeA128(ra, AsB, tid);
    loadA128(Ab0 + 64, lda, tid, ra);
    asm volatile("s_waitcnt vmcnt(4) lgkmcnt(0)" ::: "memory");
    __builtin_amdgcn_sched_barrier(0);
    __builtin_amdgcn_s_barrier();
    __builtin_amdgcn_sched_barrier(0);

    for (int t = 0; t < nt; ++t) {
        const int p = t & 1;
        const int t1 = (t + 1 < nt) ? t + 1 : nt - 1;
        const int t2 = (t + 2 < nt) ? t + 2 : nt - 1;
        stageB128(Bb0 + t1 * 64, ldw, BsB + (p ^ 1) * 8192, tid);
        writeA128(ra, AsB + (p ^ 1) * 8192, tid);
        loadA128(Ab0 + t2 * 64, lda, tid, ra);

        const ushort* Ab = AsB + p * 8192;
        const ushort* Bb = BsB + p * 8192;
#pragma unroll
        for (int ks = 0; ks < 2; ++ks) {
            bf16x8 bfr[4];
#pragma unroll
            for (int nf = 0; nf < 4; ++nf) {
                const int row = wc * 64 + nf * 16 + fr;
                bfr[nf] = *(const bf16x8*)(Bb + row * 64 + ((ks * 4 + fq) ^ (row & 7)) * 8);
            }
            bf16x8 af[2];
#pragma unroll
            for (int mf = 0; mf < 2; ++mf) {
                const int row = wr * 32 + mf * 16 + fr;
                af[mf] = *(const bf16x8*)(Ab + row * 64 + ((ks * 4 + fq) ^ (row & 7)) * 8);
            }
            __builtin_amdgcn_s_setprio(1);
#pragma unroll
            for (int mf = 0; mf < 2; ++mf)
#pragma unroll
                for (int nf = 0; nf < 4; ++nf)
                    acc[mf][nf] = __builtin_amdgcn_mfma_f32_16x16x32_bf16(
                        af[mf], bfr[nf], acc[mf][nf], 0, 0, 0);
            __builtin_amdgcn_s_setprio(0);
        }
        if (t == nt - 1) break;
        asm volatile("s_waitcnt vmcnt(4) lgkmcnt(0)" ::: "memory");
        __builtin_amdgcn_sched_barrier(0);
        __builtin_amdgcn_s_barrier();
        __builtin_amdgcn_sched_barrier(0);
    }

    const int cl = lane & 15, ch = lane >> 4;
#pragma unroll
    for (int mf = 0; mf < 2; ++mf)
#pragma unroll
        for (int nf = 0; nf < 4; ++nf)
#pragma unroll
            for (int r = 0; r < 4; ++r)
                C[(size_t)(m0 + wr * 32 + mf * 16 + ch * 4 + r) * ldc
                  + n0 + wc * 64 + nf * 16 + cl] = acc[mf][nf][r];
}

__global__ __launch_bounds__(512, 4)
void gemm128f(const float* __restrict__ A, const ushort* __restrict__ W,
              float* __restrict__ C, int gx, int nwg)
{
    __shared__ ushort As[2 * 128 * 64];
    __shared__ ushort Bs[2 * 128 * 64];
    gemm128f_body(A, W, C, SALSZ, SALSZ, 1024, SALSZ, gx, nwg, blockIdx.x, As, Bs, threadIdx.x);
}

// ======== 128x128 GEMM body, bf16 A/B, 2-phase; optional wait-flag (per slice),
// ======== optional signal-flag, optional write-through C, optional rbias. ========
__device__ __forceinline__ void gemm128b_body(
    const ushort* __restrict__ A, const ushort* __restrict__ W, float* __restrict__ C,
    int lda, int ldw, int ldc, int K, int gx, int nwg, int bid,
    unsigned int* wflag, unsigned int wcnt, unsigned int* sflag, bool wt,
    const float* __restrict__ rbias,
    ushort* AsB, ushort* BsB, int tid)
{
    const int lane = tid & 63, wid = tid >> 6;
    {   // bijective XCD-chunked swizzle
        const int q = nwg >> 3, r = nwg & 7;
        const int xcd = bid & 7, o = bid >> 3;
        bid = (xcd < r) ? xcd * (q + 1) + o : r * (q + 1) + (xcd - r) * q + o;
    }
    const int m0 = (bid / gx) * 128, n0 = (bid % gx) * 128;

    if (wflag) gbar_wait(wflag + (m0 >> 9), wcnt);   // A slice ready (same-kernel producer)

    const int wr = wid >> 1, wc = wid & 1;
    const int fr = lane & 15, fq = lane >> 4;

    f32x4 acc[2][4] = {};
    const int nt = K / 64;
    const ushort* Ab0 = A + (size_t)m0 * lda;
    const ushort* Bb0 = W + (size_t)n0 * ldw;

    stageB128(Ab0, lda, AsB, tid);
    stageB128(Bb0, ldw, BsB, tid);
    __syncthreads();

    for (int t = 0; t < nt; ++t) {
        const int p = t & 1;
        if (t + 1 < nt) {
            stageB128(Ab0 + (t + 1) * 64, lda, AsB + (p ^ 1) * 8192, tid);
            stageB128(Bb0 + (t + 1) * 64, ldw, BsB + (p ^ 1) * 8192, tid);
        }
        const ushort* Ab = AsB + p * 8192;
        const ushort* Bb = BsB + p * 8192;
#pragma unroll
        for (int ks = 0; ks < 2; ++ks) {
            bf16x8 bfr[4];
#pragma unroll
            for (int nf = 0; nf < 4; ++nf) {
                const int row = wc * 64 + nf * 16 + fr;
                bfr[nf] = *(const bf16x8*)(Bb + row * 64 + ((ks * 4 + fq) ^ (row & 7)) * 8);
            }
            bf16x8 af[2];
#pragma unroll
            for (int mf = 0; mf < 2; ++mf) {
                const int row = wr * 32 + mf * 16 + fr;
                af[mf] = *(const bf16x8*)(Ab + row * 64 + ((ks * 4 + fq) ^ (row & 7)) * 8);
            }
#pragma unroll
            for (int mf = 0; mf < 2; ++mf)
#pragma unroll
                for (int nf = 0; nf < 4; ++nf)
                    acc[mf][nf] = __builtin_amdgcn_mfma_f32_16x16x32_bf16(
                        af[mf], bfr[nf], acc[mf][nf], 0, 0, 0);
        }
        if (t == nt - 1) break;
        __syncthreads();
    }

    const int cl = lane & 15, ch = lane >> 4;
#pragma unroll
    for (int mf = 0; mf < 2; ++mf)
#pragma unroll
        for (int nf = 0; nf < 4; ++nf)
#pragma unroll
            for (int r = 0; r < 4; ++r) {
                const int mm = m0 + wr * 32 + mf * 16 + ch * 4 + r;
                const int nn = n0 + wc * 64 + nf * 16 + cl;
                float v = acc[mf][nf][r];
                if (rbias) v += rbias[(size_t)(mm & 511) * ldc + nn];
                if (wt) st_f32(C + (size_t)mm * ldc + nn, v);
                else    C[(size_t)mm * ldc + nn] = v;
            }
    if (sflag) {
        __syncthreads();   // drain write-throughs
        if (tid == 0) atomicAdd(sflag + (m0 >> 9), 1u);
    }
}

// ---------------- merged: encoder chains (0..127) + sd GEMM (128..927) ----------------
struct EncArgs {
    const ushort *WHse, *WHpe;
    const float  *xg_se;
    const float  *enc_pos;
    const float  *se_b1, *se_b2, *pe_b1, *pe_b2;
    const float  *pe_Wih;
    ushort       *conc;      // [16][512][512]
    float        *SE_C, *PE_C;
    unsigned int *bar;       // 16 groups x 16 steps, degree 8
};

__global__ __launch_bounds__(512, 4)
void enc_sd(EncArgs A, const float* __restrict__ sdA, const ushort* __restrict__ sdW,
            float* __restrict__ sdC)
{
    __shared__ ushort sh[34816];
    const int tid = threadIdx.x;

    if (blockIdx.x >= 128) {
        gemm128f_body(sdA, sdW, sdC, SALSZ, SALSZ, 1024, SALSZ, 8, 800,
                      (int)blockIdx.x - 128, sh, sh + 16384, tid);
        return;
    }

    const int lane = tid & 63, w = tid >> 6;
    const int role  = blockIdx.x >> 6;
    const int rem   = blockIdx.x & 63;
    const int btile = rem & 7, usup = rem >> 3;
    const int b0 = btile * 64, ub = usup * 32;
    const int usub = w & 1, bsub = w >> 1;
    const int u0t = ub + usub * 16;
    const int grp = role * 8 + btile;
    const int fr = lane & 15, fq = lane >> 4;
    const int u = u0t + fr;
    const int ul = usub * 16 + fr;
    const int coff = role ? 256 : 0;
    ushort* Ws0 = sh + usub * 16384;
    ushort (*hloc)[32] = (ushort(*)[32])(sh + 32768);

    stage_wtile(role ? A.WHpe : A.WHse, HID, u0t, Ws0, lane, bsub);

    const float* b1 = role ? A.pe_b1 : A.se_b1;
    const float* b2 = role ? A.pe_b2 : A.se_b2;
    float bias[4], wxs[4][3];
#pragma unroll
    for (int g = 0; g < 4; ++g) {
        bias[g] = b1[g * HID + u] + b2[g * HID + u];
        wxs[g][0] = wxs[g][1] = wxs[g][2] = 0.0f;
        if (role) {
            wxs[g][0] = A.pe_Wih[(g * HID + u) * 3 + 0];
            wxs[g][1] = A.pe_Wih[(g * HID + u) * 3 + 1];
            wxs[g][2] = A.pe_Wih[(g * HID + u) * 3 + 2];
        }
    }
    float c[4] = {0.f, 0.f, 0.f, 0.f};
    __syncthreads();

    for (int t = 0; t < MENC; ++t) {
        float xg[4][4];
#pragma unroll
        for (int r = 0; r < 4; ++r) {
            const int b = b0 + bsub * 16 + fq * 4 + r;
            if (role) {
                const float* xp = A.enc_pos + ((size_t)b * MENC + t) * 3;
                xg[r][0] = xp[0]; xg[r][1] = xp[1]; xg[r][2] = xp[2]; xg[r][3] = 0.f;
            } else {
#pragma unroll
                for (int g = 0; g < 4; ++g)
                    xg[r][g] = A.xg_se[((size_t)b * MENC + t) * 1024 + g * HID + u];
            }
        }
        if (t > 0) gbar_wait(A.bar + grp * MENC + (t - 1), 8);
        f32x4 acc[4] = {};
        if (t > 0)
            cell_g(A.conc + ((size_t)(t - 1) * 512 + b0 + bsub * 16) * 512 + coff, 512,
                   Ws0, acc, lane);
#pragma unroll
        for (int r = 0; r < 4; ++r) {
            const int bl = bsub * 16 + fq * 4 + r;
            const int b = b0 + bl;
            float gv[4];
#pragma unroll
            for (int g = 0; g < 4; ++g) {
                float v = acc[g][r] + bias[g];
                if (role) v += xg[r][0] * wxs[g][0] + xg[r][1] * wxs[g][1] + xg[r][2] * wxs[g][2];
                else      v += xg[r][g];
                gv[g] = v;
            }
            const float cn = sigmf(gv[1]) * c[r] + sigmf(gv[0]) * tanhf(gv[2]);
            const float hn = sigmf(gv[3]) * tanhf(cn);
            c[r] = cn;
            hloc[bl][ul] = f2bf(hn);
            if (t == MENC - 1) (role ? A.PE_C : A.SE_C)[(size_t)b * HID + u] = cn;
        }
        __syncthreads();
        {
            const int row = tid >> 3, c8 = tid & 7;
            const unsigned long long v = *(const unsigned long long*)&hloc[row][c8 * 4];
            st_u64(A.conc + ((size_t)t * 512 + b0 + row) * 512 + coff + ub + c8 * 4, v);
        }
        if (t != MENC - 1) gbar_arrive(A.bar + grp * MENC + t);
    }
}

// ================= phase-3 mega-kernel: mid chains + fe GEMM + GBIAS-tn + dec + xh2 =================
// block layout: 0..127 chains | 128..639 fe GEMM | 640..767 tn | 768..831 dec | 832..1631 xh2
struct P3Args {
    // mid chains
    const ushort *WHsd, *WHfe;
    const float  *xg_sd, *xg_fe;
    const float  *sd_b1, *sd_b2, *fe_b1, *fe_b2;
    const ushort *conc;
    const float  *SE_C;
    ushort       *SDB;       // [25][512][256]
    ushort       *FEB;       // [16][512][256]
    float        *FEH, *FE_C;
    unsigned int *bar;       // 16 grp x 25, degree 8
    unsigned int *fe_done;   // [16], degree 32
    unsigned int *sdb_done;  // [25], degree 64
    // fe GEMM
    const ushort *feW;
    float        *feC;       // XG_FE
    // tn (GBIAS)
    const float  *fd_Whh, *fd_b1, *fd_b2;
    float        *GBIAS;
    unsigned int *fe_fin;    // degree 64
    unsigned int *gb_done;   // degree 128
    // xh2 GEMM
    const ushort *xW;        // WFD (h2 cols)
    float        *xh2C;      // BIG2
    unsigned int *xh2_done;  // [25], degree 32
    // dec
    const ushort *WHpd, *WFDh, *peF;
    const float  *PE_C;
    const float  *pd_b1, *pd_b2, *pd_Wih;
    const float  *G, *c3, *dec_pos;
    ushort       *H1;        // [25][512][256]
    float        *DELTA;     // pre-zeroed
    float        *out;
    unsigned int *dbar;      // 4 btiles x 50, degree 16
};

// ---- tn role: GBIAS = FEH @ fd_Whh^T + bih + bhh (512-thread, 64x64 tile) ----
__device__ __forceinline__ void tn_body(const P3Args& A, int idx, ushort* shm, int tid)
{
    gbar_wait(A.fe_fin, 64);                 // FEH fully written (write-through)
    float* As = (float*)shm;                 // [16][68]
    float* Ws = As + 16 * 68;
    const int m0 = (idx >> 4) * 64, n0 = (idx & 15) * 64;
    const int lr = tid >> 3, kc = tid & 7;
    const int tx = tid & 15, ty = tid >> 4;  // ty 0..31
    float acc[2][4] = {};
    for (int k0 = 0; k0 < HID; k0 += 16) {
        const float a0 = A.FEH[(size_t)(m0 + lr) * HID + k0 + kc * 2];
        const float a1 = A.FEH[(size_t)(m0 + lr) * HID + k0 + kc * 2 + 1];
        const float w0 = A.fd_Whh[(size_t)(n0 + lr) * HID + k0 + kc * 2];
        const float w1 = A.fd_Whh[(size_t)(n0 + lr) * HID + k0 + kc * 2 + 1];
        __syncthreads();
        As[(kc * 2) * 68 + lr] = a0; As[(kc * 2 + 1) * 68 + lr] = a1;
        Ws[(kc * 2) * 68 + lr] = w0; Ws[(kc * 2 + 1) * 68 + lr] = w1;
        __syncthreads();
#pragma unroll
        for (int kk = 0; kk < 16; ++kk) {
            const float av0 = As[kk * 68 + ty * 2], av1 = As[kk * 68 + ty * 2 + 1];
            const float4 wv = *(const float4*)&Ws[kk * 68 + tx * 4];
            acc[0][0] += av0 * wv.x; acc[0][1] += av0 * wv.y; acc[0][2] += av0 * wv.z; acc[0][3] += av0 * wv.w;
            acc[1][0] += av1 * wv.x; acc[1][1] += av1 * wv.y; acc[1][2] += av1 * wv.z; acc[1][3] += av1 * wv.w;
        }
    }
#pragma unroll
    for (int i = 0; i < 2; ++i) {
        const int m = m0 + ty * 2 + i;
#pragma unroll
        for (int j = 0; j < 4; ++j) {
            const int n = n0 + tx * 4 + j;
            st_f32(A.GBIAS + (size_t)m * 1024 + n, acc[i][j] + A.fd_b1[n] + A.fd_b2[n]);
        }
    }
    __syncthreads();
    if (tid == 0) atomicAdd(A.gb_done, 1u);
}

// ---- dec role: 128b x 16u per block (64 blocks = 4 btiles x 16 usups), degree-16 barriers ----
__device__ __forceinline__ void dec_body(const P3Args& A, int idx, ushort* shm, int tid)
{
    ushort* Wpd = shm;                                  // 32 KB
    ushort* Wfd = shm + 16384;                          // 32 KB
    ushort (*hloc)[16] = (ushort(*)[16])(shm + 32768);  // [128][16]
    float* pred_lds = (float*)(shm + 34816);            // 384 floats
    const int lane = tid & 63, w = tid >> 6;
    const int btile = idx & 3, usup = idx >> 2;
    const int b0 = btile * 128, u0t = usup * 16;
    const int bsub = w;                                 // 0..7 -> 16 b each
    const int fr = lane & 15, fq = lane >> 4;
    const int u = u0t + fr;
    unsigned int* bars = A.dbar + btile * 2 * HWIN;

    if (w < 4) stage_wtile(A.WHpd, HID, u0t, Wpd, lane, w);
    else       stage_wtile(A.WFDh, 512, u0t, Wfd, lane, w - 4);

    float pdb[4], wxs[4][3], cf[4], c1[4], Gu[3];
#pragma unroll
    for (int g = 0; g < 4; ++g) {
        pdb[g] = A.pd_b1[g * HID + u] + A.pd_b2[g * HID + u];
        wxs[g][0] = A.pd_Wih[(g * HID + u) * 3 + 0];
        wxs[g][1] = A.pd_Wih[(g * HID + u) * 3 + 1];
        wxs[g][2] = A.pd_Wih[(g * HID + u) * 3 + 2];
    }
#pragma unroll
    for (int r = 0; r < 4; ++r)
        c1[r] = A.PE_C[(size_t)(b0 + bsub * 16 + fq * 4 + r) * HID + u];
    Gu[0] = A.G[u]; Gu[1] = A.G[HID + u]; Gu[2] = A.G[2 * HID + u];
    const float c3r = (tid < 384) ? A.c3[tid % 3] : 0.0f;
    if (tid < 384) pred_lds[tid] = A.dec_pos[(size_t)(b0 + tid / 3) * 3 + tid % 3];

    gbar_wait(A.gb_done, 128);   // implies fe_fin (FE_C visible); syncthreads drains W staging
#pragma unroll
    for (int r = 0; r < 4; ++r)
        cf[r] = A.FE_C[(size_t)(b0 + bsub * 16 + fq * 4 + r) * HID + u];

    for (int t = 0; t < HWIN; ++t) {
        f32x4 acc[4] = {};
        if (t == 0) cell_g(A.peF + (size_t)(b0 + bsub * 16) * 512, 512, Wpd, acc, lane);
        else        cell_g(A.H1 + ((size_t)(t - 1) * BATCH + b0 + bsub * 16) * HID, HID,
                           Wpd, acc, lane);
        if (t > 0) {
            gbar_wait(bars + 2 * (t - 1) + 1, 16);
            if (tid < 384) {
                pred_lds[tid] += A.DELTA[((size_t)(t - 1) * 512 + b0 + tid / 3) * 3 + tid % 3] + c3r;
                if (usup == 0)
                    A.out[((size_t)(b0 + tid / 3) * HWIN + (t - 1)) * 3 + tid % 3] = pred_lds[tid];
            }
            __syncthreads();
        }
#pragma unroll
        for (int r = 0; r < 4; ++r) {
            const int bl = bsub * 16 + fq * 4 + r;
            const float x0 = pred_lds[bl * 3 + 0];
            const float x1 = pred_lds[bl * 3 + 1];
            const float x2 = pred_lds[bl * 3 + 2];
            float gv[4];
#pragma unroll
            for (int g = 0; g < 4; ++g)
                gv[g] = acc[g][r] + pdb[g] + x0 * wxs[g][0] + x1 * wxs[g][1] + x2 * wxs[g][2];
            const float cn = sigmf(gv[1]) * c1[r] + sigmf(gv[0]) * tanhf(gv[2]);
            const float hn = sigmf(gv[3]) * tanhf(cn);
            c1[r] = cn;
            hloc[bl][fr] = f2bf(hn);
        }
        __syncthreads();
        {
            const int row = tid >> 2, c4 = tid & 3;
            const unsigned long long v = *(const unsigned long long*)&hloc[row][c4 * 4];
            st_u64(A.H1 + ((size_t)t * BATCH + b0 + row) * 256 + u0t + c4 * 4, v);
        }
        gbar_arrive(bars + 2 * t);
        gbar_wait(A.xh2_done + t, 32);     // xh2 slice t ready (in-kernel producer, GBIAS folded)
        float xh[4][4];
#pragma unroll
        for (int r = 0; r < 4; ++r) {
            const int b = b0 + bsub * 16 + fq * 4 + r;
#pragma unroll
            for (int g = 0; g < 4; ++g)
                xh[r][g] = A.xh2C[((size_t)t * 512 + b) * 1024 + g * HID + u];
        }
        gbar_wait(bars + 2 * t, 16);
        {
            f32x4 accB[4] = {};
            cell_g(A.H1 + ((size_t)t * BATCH + b0 + bsub * 16) * HID, HID, Wfd, accB, lane);
#pragma unroll
            for (int r = 0; r < 4; ++r) {
                const int b = b0 + bsub * 16 + fq * 4 + r;
                float gv[4];
#pragma unroll
                for (int g = 0; g < 4; ++g)
                    gv[g] = accB[g][r] + xh[r][g];
                const float cn = sigmf(gv[1]) * cf[r] + sigmf(gv[0]) * tanhf(gv[2]);
                const float hn = sigmf(gv[3]) * tanhf(cn);
                float p0 = hn * Gu[0], p1 = hn * Gu[1], p2 = hn * Gu[2];
#pragma unroll
                for (int s = 1; s < 16; s <<= 1) {
                    p0 += __shfl_xor(p0, s);
                    p1 += __shfl_xor(p1, s);
                    p2 += __shfl_xor(p2, s);
                }
                if (fr == 0) {
                    float* d = A.DELTA + ((size_t)t * 512 + b) * 3;
                    atomicAdd(d + 0, p0); atomicAdd(d + 1, p1); atomicAdd(d + 2, p2);
                }
            }
        }
        gbar_arrive(bars + 2 * t + 1);
    }
    gbar_wait(bars + 2 * (HWIN - 1) + 1, 16);
    if (tid < 384) {
        pred_lds[tid] += A.DELTA[((size_t)(HWIN - 1) * 512 + b0 + tid / 3) * 3 + tid % 3] + c3r;
        if (usup == 0)
            A.out[((size_t)(b0 + tid / 3) * HWIN + (HWIN - 1)) * 3 + tid % 3] = pred_lds[tid];
    }
}

__global__ __launch_bounds__(512, 4)
void mid_dec(P3Args A)
{
    __shared__ ushort sh[35584];   // 71168 B -> 2 blocks/CU
    const int tid = threadIdx.x;
    const int blk = (int)blockIdx.x;

    if (blk >= 832) {
        // xh2 GEMM: needs GBIAS (rbias) + SDB slice; write-through C + xh2_done
        gbar_wait(A.gb_done, 128);
        gemm128b_body(A.SDB, A.xW, A.xh2C, 256, 512, 1024, 256, 8, 800,
                      blk - 832, A.sdb_done, 64, A.xh2_done, true, A.GBIAS,
                      sh, sh + 16384, tid);
        return;
    }
    if (blk >= 768) { dec_body(A, blk - 768, sh, tid); return; }
    if (blk >= 640) { tn_body(A, blk - 640, sh, tid); return; }
    if (blk >= 128) {
        // fe GEMM: write-through C + fe_done slice flags (same-kernel mid readers)
        gemm128b_body(A.conc, A.feW, A.feC, 512, 512, 1024, 512, 8, 512,
                      blk - 128, nullptr, 0, A.fe_done, true, nullptr,
                      sh, sh + 16384, tid);
        return;
    }

    // ---- mid chains: sd (25 steps) + fe (16 steps) ----
    const int lane = tid & 63, w = tid >> 6;
    const int role  = blk >> 6;
    const int rem   = blk & 63;
    const int btile = rem & 7, usup = rem >> 3;
    const int b0 = btile * 64, ub = usup * 32;
    const int usub = w & 1, bsub = w >> 1;
    const int u0t = ub + usub * 16;
    const int grp = role * 8 + btile;
    const int fr = lane & 15, fq = lane >> 4;
    const int u = u0t + fr;
    const int ul = usub * 16 + fr;
    const int NT = role ? MENC : HWIN;
    ushort* Ws0 = sh + usub * 16384;
    ushort (*hloc)[32] = (ushort(*)[32])(sh + 32768);

    stage_wtile(role ? A.WHfe : A.WHsd, HID, u0t, Ws0, lane, bsub);

    const float* b1 = role ? A.fe_b1 : A.sd_b1;
    const float* b2 = role ? A.fe_b2 : A.sd_b2;
    float bias[4];
#pragma unroll
    for (int g = 0; g < 4; ++g) bias[g] = b1[g * HID + u] + b2[g * HID + u];

    float c[4];
#pragma unroll
    for (int r = 0; r < 4; ++r) {
        const int b = b0 + bsub * 16 + fq * 4 + r;
        c[r] = role ? 0.0f : A.SE_C[(size_t)b * HID + u];
    }
    __syncthreads();

    for (int t = 0; t < NT; ++t) {
        if (role) gbar_wait(A.fe_done + t, 32);   // XG_FE slice t ready
        float xg[4][4];
#pragma unroll
        for (int r = 0; r < 4; ++r) {
            const int b = b0 + bsub * 16 + fq * 4 + r;
#pragma unroll
            for (int g = 0; g < 4; ++g)
                xg[r][g] = role ? A.xg_fe[((size_t)t * 512 + b) * 1024 + g * HID + u]
                                : A.xg_sd[((size_t)b * HWIN + t) * 1024 + g * HID + u];
        }
        if (t > 0) gbar_wait(A.bar + grp * HWIN + (t - 1), 8);
        f32x4 acc[4] = {};
        if (role == 0) {
            if (t == 0) cell_g(A.conc + ((size_t)15 * 512 + b0 + bsub * 16) * 512, 512,
                               Ws0, acc, lane);
            else        cell_g(A.SDB + ((size_t)(t - 1) * 512 + b0 + bsub * 16) * HID, HID,
                               Ws0, acc, lane);
        } else if (t > 0) {
            cell_g(A.FEB + ((size_t)(t - 1) * BATCH + b0 + bsub * 16) * HID, HID,
                   Ws0, acc, lane);
        }
#pragma unroll
        for (int r = 0; r < 4; ++r) {
            const int bl = bsub * 16 + fq * 4 + r;
            const int b = b0 + bl;
            float gv[4];
#pragma unroll
            for (int g = 0; g < 4; ++g)
                gv[g] = acc[g][r] + bias[g] + xg[r][g];
            const float cn = sigmf(gv[1]) * c[r] + sigmf(gv[0]) * tanhf(gv[2]);
            const float hn = sigmf(gv[3]) * tanhf(cn);
            c[r] = cn;
            hloc[bl][ul] = f2bf(hn);
            if (role == 1 && t == MENC - 1) {
                st_f32(A.FEH + (size_t)b * HID + u, hn);    // write-through: same-kernel tn reads
                st_f32(A.FE_C + (size_t)b * HID + u, cn);   // write-through: same-kernel dec reads
            }
        }
        __syncthreads();
        {
            const int row = tid >> 3, c8 = tid & 7;
            const unsigned long long v = *(const unsigned long long*)&hloc[row][c8 * 4];
            ushort* dst = role ? (A.FEB + ((size_t)t * BATCH + b0 + row) * 256 + ub + c8 * 4)
                               : (A.SDB + ((size_t)t * 512 + b0 + row) * 256 + ub + c8 * 4);
            st_u64(dst, v);
        }
        __syncthreads();   // drain h stores (and FEH/FE_C at last fe step) before signaling
        if (tid == 0) {
            if (role == 0) atomicAdd(A.sdb_done + t, 1u);
            if (t != NT - 1) atomicAdd(A.bar + grp * HWIN + t, 1u);
        }
    }
    if (role == 1) {
        if (tid == 0) atomicAdd(A.fe_fin, 1u);   // FEH/FE_C drained by loop's final syncthreads
    }
}

// ---------------- G = out_W @ f2_W, c3 = out_b + out_W @ f2_b ----------------
__global__ __launch_bounds__(256)
void precompute_G(const float* __restrict__ f2W, const float* __restrict__ f2b,
                  const float* __restrict__ outW, const float* __restrict__ outb,
                  float* __restrict__ G, float* __restrict__ c3)
{
    const int k = threadIdx.x;
    float g0 = 0.f, g1 = 0.f, g2 = 0.f;
    for (int n = 0; n < HID; ++n) {
        const float w = f2W[n * HID + k];
        g0 += outW[n] * w;
        g1 += outW[HID + n] * w;
        g2 += outW[2 * HID + n] * w;
    }
    G[k] = g0; G[HID + k] = g1; G[2 * HID + k] = g2;
    if (k < 3) {
        float s = outb[k];
        for (int n = 0; n < HID; ++n) s += outW[k * HID + n] * f2b[n];
        c3[k] = s;
    }
}

extern "C" void kernel_launch(void* const* d_in, const int* in_sizes, int n_in,
                              void* d_out, int out_size, void* d_ws, size_t ws_size,
                              hipStream_t stream)
{
    (void)in_sizes; (void)n_in; (void)out_size; (void)ws_size;
    const float* enc_pos = (const float*)d_in[0];
    const float* enc_sal = (const float*)d_in[1];
    const float* dec_pos = (const float*)d_in[2];
    const float* dec_sal = (const float*)d_in[3];
    const float *pe_Wih = (const float*)d_in[4],  *pe_Whh = (const float*)d_in[5],
                *pe_bih = (const float*)d_in[6],  *pe_bhh = (const float*)d_in[7];
    const float *se_Wih = (const float*)d_in[8],  *se_Whh = (const float*)d_in[9],
                *se_bih = (const float*)d_in[10], *se_bhh = (const float*)d_in[11];
    const float *fe_Wih = (const float*)d_in[12], *fe_Whh = (const float*)d_in[13],
                *fe_bih = (const float*)d_in[14], *fe_bhh = (const float*)d_in[15];
    const float *pd_Wih = (const float*)d_in[16], *pd_Whh = (const float*)d_in[17],
                *pd_bih = (const float*)d_in[18], *pd_bhh = (const float*)d_in[19];
    const float *sd_Wih = (const float*)d_in[20], *sd_Whh = (const float*)d_in[21],
                *sd_bih = (const float*)d_in[22], *sd_bhh = (const float*)d_in[23];
    const float *fd_Wih = (const float*)d_in[24], *fd_Whh = (const float*)d_in[25],
                *fd_bih = (const float*)d_in[26], *fd_bhh = (const float*)d_in[27];
    const float *f2_W = (const float*)d_in[28], *f2_b = (const float*)d_in[29];
    const float *out_W = (const float*)d_in[30], *out_b = (const float*)d_in[31];
    float* out = (float*)d_out;
    float* ws  = (float*)d_ws;

    size_t off = 0;
    float* XG_SE = ws + off; off += (size_t)8192 * 1024;
    float* XG_FE = ws + off; off += (size_t)8192 * 1024;
    float* BIG   = ws + off; off += (size_t)12800 * 1024;
    float* BIG2  = ws + off; off += (size_t)12800 * 1024;
    float* GBIAS = ws + off; off += (size_t)BATCH * 1024;
    float* PE_C  = ws + off; off += BH;
    float* SE_C  = ws + off; off += BH;
    float* FE_C  = ws + off; off += BH;
    float* FEH   = ws + off; off += BH;
    float* Gm    = ws + off; off += 1024;
    float* C3    = ws + off; off += 8;
    float* DELTA = ws + off; off += (size_t)HWIN * BATCH * 3 + 64;
    unsigned int* BAR = (unsigned int*)(ws + off); off += 1280;
    ushort* WSE  = (ushort*)(ws + off); off += ((size_t)1024 * 4096) / 2;
    ushort* WSD  = (ushort*)(ws + off); off += ((size_t)1024 * 4096) / 2;
    ushort* WFE  = (ushort*)(ws + off); off += ((size_t)1024 * 512) / 2;
    ushort* WFD  = (ushort*)(ws + off); off += ((size_t)1024 * 512) / 2;
    ushort* WHpe = (ushort*)(ws + off); off += ((size_t)1024 * 256) / 2;
    ushort* WHse = (ushort*)(ws + off); off += ((size_t)1024 * 256) / 2;
    ushort* WHfe = (ushort*)(ws + off); off += ((size_t)1024 * 256) / 2;
    ushort* WHsd = (ushort*)(ws + off); off += ((size_t)1024 * 256) / 2;
    ushort* WHpd = (ushort*)(ws + off); off += ((size_t)1024 * 256) / 2;
    ushort* CONC = (ushort*)(ws + off); off += ((size_t)MENC * 512 * 512) / 2;
    ushort* SDB  = (ushort*)(ws + off); off += ((size_t)HWIN * BH) / 2;
    ushort* FEB  = (ushort*)(ws + off); off += ((size_t)MENC * BH) / 2;
    ushort* H1   = (ushort*)(ws + off); off += ((size_t)HWIN * BH) / 2;

    unsigned int* FE_DONE  = BAR + 1100;   // 16
    unsigned int* SDB_DONE = BAR + 1160;   // 25
    unsigned int* FE_FIN   = BAR + 1200;   // 1
    unsigned int* GB_DONE  = BAR + 1204;   // 1
    unsigned int* XH2_DONE = BAR + 1220;   // 25

    // DELTA and BAR contiguous: one memset (covers all flags)
    hipMemsetAsync(DELTA, 0, ((size_t)HWIN * BATCH * 3 + 64 + 1280) * 4, stream);

    // ---- all 9 weight conversions in ONE launch ----
    {
        Cvt9 a;
        const float* srcs[9] = { se_Wih, sd_Wih, fe_Wih, fd_Wih, pe_Whh, se_Whh, fe_Whh, sd_Whh, pd_Whh };
        ushort*      dsts[9] = { WSE,    WSD,    WFE,    WFD,    WHpe,   WHse,   WHfe,   WHsd,   WHpd };
        const int    n4s[9]  = { 1024*4096/4, 1024*4096/4, 1024*512/4, 1024*512/4,
                                 1024*256/4, 1024*256/4, 1024*256/4, 1024*256/4, 1024*256/4 };
        int acc9 = 0;
        for (int i = 0; i < 9; ++i) { a.s[i] = srcs[i]; a.d[i] = dsts[i]; acc9 += n4s[i]; a.end[i] = acc9; }
        cvt_multi<<<(acc9 + 255) / 256, 256, 0, stream>>>(a);
    }
    precompute_G<<<1, 256, 0, stream>>>(f2_W, f2_b, out_W, out_b, Gm, C3);

    // ---- se x-proj (alone) ----
    gemm128f<<<512, 512, 0, stream>>>(enc_sal, WSE, XG_SE, 8, 512);

    // ---- MERGED: encoder chains (128) + sd x-proj GEMM (800) ----
    {
        EncArgs a;
        a.WHse = WHse; a.WHpe = WHpe; a.xg_se = XG_SE; a.enc_pos = enc_pos;
        a.se_b1 = se_bih; a.se_b2 = se_bhh; a.pe_b1 = pe_bih; a.pe_b2 = pe_bhh;
        a.pe_Wih = pe_Wih; a.conc = CONC; a.SE_C = SE_C; a.PE_C = PE_C;
        a.bar = BAR;
        enc_sd<<<928, 512, 0, stream>>>(a, dec_sal, WSD, BIG);
    }

    // ---- MEGA-MERGED phase 3: mid chains + fe GEMM + GBIAS + dec + xh2 (1632 blocks) ----
    {
        P3Args a;
        a.WHsd = WHsd; a.WHfe = WHfe; a.xg_sd = BIG; a.xg_fe = XG_FE;
        a.sd_b1 = sd_bih; a.sd_b2 = sd_bhh; a.fe_b1 = fe_bih; a.fe_b2 = fe_bhh;
        a.conc = CONC; a.SE_C = SE_C; a.SDB = SDB; a.FEB = FEB;
        a.FEH = FEH; a.FE_C = FE_C;
        a.bar = BAR + 256; a.fe_done = FE_DONE; a.sdb_done = SDB_DONE;
        a.feW = WFE; a.feC = XG_FE;
        a.fd_Whh = fd_Whh; a.fd_b1 = fd_bih; a.fd_b2 = fd_bhh; a.GBIAS = GBIAS;
        a.fe_fin = FE_FIN; a.gb_done = GB_DONE;
        a.xW = WFD; a.xh2C = BIG2; a.xh2_done = XH2_DONE;
        a.WHpd = WHpd; a.WFDh = WFD + 256;
        a.peF = CONC + ((size_t)15 * 512) * 512 + 256;
        a.PE_C = PE_C;
        a.pd_b1 = pd_bih; a.pd_b2 = pd_bhh; a.pd_Wih = pd_Wih;
        a.G = Gm; a.c3 = C3; a.dec_pos = dec_pos;
        a.H1 = H1; a.DELTA = DELTA; a.out = out; a.dbar = BAR + 656;
        mid_dec<<<1632, 512, 0, stream>>>(a);
    }
}